// Round 3
// baseline (43.737 us; speedup 1.0000x reference)
//
#include <hip/hip_runtime.h>

#define TPB 256   // threads per block; each thread owns 4 matrices (2 packed v2f streams)

typedef float v2f __attribute__((ext_vector_type(2)));
typedef int   v2i __attribute__((ext_vector_type(2)));

static __device__ __forceinline__ v2f sqrt2(v2f a){
    v2f r; r.x = __builtin_amdgcn_sqrtf(a.x); r.y = __builtin_amdgcn_sqrtf(a.y); return r;
}
static __device__ __forceinline__ v2f rsq2(v2f a){
    v2f r; r.x = __builtin_amdgcn_rsqf(a.x); r.y = __builtin_amdgcn_rsqf(a.y); return r;
}
static __device__ __forceinline__ v2f csign2(v2f x, v2f y){
    v2f r; r.x = copysignf(x.x, y.x); r.y = copysignf(x.y, y.y); return r;
}
static __device__ __forceinline__ v2f fabs2(v2f x){
    v2f r; r.x = fabsf(x.x); r.y = fabsf(x.y); return r;
}
static __device__ __forceinline__ v2f sel2(v2i m, v2f a, v2f b){
    v2f r; r.x = m.x ? a.x : b.x; r.y = m.y ? a.y : b.y; return r;
}
// Jacobi/column rotation: p' = c*p - s*q ; q' = s*p + c*q
static __device__ __forceinline__ void rot2(v2f &p, v2f &q, v2f c, v2f s){
    v2f x = p, y = q; p = c*x - s*y; q = s*x + c*y;
}
// QR rotation: p' = c*p + s*q ; q' = c*q - s*p
static __device__ __forceinline__ void rotg2(v2f &p, v2f &q, v2f c, v2f s){
    v2f x = p, y = q; p = c*x + s*y; q = c*y - s*x;
}

// Exact cyclic-Jacobi rotation (2 transcendentals), branchless.
static __device__ __forceinline__ void jrot2(v2f &app, v2f &aqq, v2f &apq,
                                             v2f &arp, v2f &arq,
                                             v2f &v0p, v2f &v1p, v2f &v2p,
                                             v2f &v0q, v2f &v1q, v2f &v2q)
{
    v2f d   = aqq - app;
    v2f w   = apq + apq;
    v2f nrm = d*d + w*w;
    v2f rr  = sqrt2(nrm);
    v2f sr  = csign2(rr, d);
    v2f den = d + sr;
    v2f inv = rsq2(den*den + w*w);
    v2f c   = fabs2(den) * inv;
    v2f s   = w * csign2(inv, den);
    v2i tiny = nrm < (v2f)1e-30f;
    c = sel2(tiny, (v2f)1.0f, c);
    s = sel2(tiny, (v2f)0.0f, s);
    v2f sum = app + aqq;
    v2f lo  = 0.5f*(sum - sr);
    app = lo; aqq = sum - lo; apq = (v2f)0.0f;
    rot2(arp, arq, c, s);
    rot2(v0p, v0q, c, s);
    rot2(v1p, v1q, c, s);
    rot2(v2p, v2q, c, s);
}

static __device__ __forceinline__ void givens2(v2f a1, v2f a2,
    v2f &bi0, v2f &bi1, v2f &bi2, v2f &bj0, v2f &bj1, v2f &bj2,
    v2f &ui0, v2f &ui1, v2f &ui2, v2f &uj0, v2f &uj1, v2f &uj2)
{
    v2f d  = a1*a1 + a2*a2;
    v2f rr = rsq2(d);
    v2i ok = d > (v2f)1e-30f;
    v2f c  = sel2(ok, a1*rr, (v2f)1.0f);
    v2f s  = sel2(ok, a2*rr, (v2f)0.0f);
    rotg2(bi0, bj0, c, s);
    rotg2(bi1, bj1, c, s);
    rotg2(bi2, bj2, c, s);
    rotg2(ui0, uj0, c, s);
    rotg2(ui1, uj1, c, s);
    rotg2(ui2, uj2, c, s);
}

// Full SO(3) projection for 2 packed matrices. In: m**, out: r**.
static __device__ __forceinline__ void solve2(
    v2f m00, v2f m01, v2f m02,
    v2f m10, v2f m11, v2f m12,
    v2f m20, v2f m21, v2f m22,
    v2f &r00, v2f &r01, v2f &r02,
    v2f &r10, v2f &r11, v2f &r12,
    v2f &r20, v2f &r21, v2f &r22)
{
    // A = M^T M
    v2f a00 = m00*m00 + m10*m10 + m20*m20;
    v2f a11 = m01*m01 + m11*m11 + m21*m21;
    v2f a22 = m02*m02 + m12*m12 + m22*m22;
    v2f a01 = m00*m01 + m10*m11 + m20*m21;
    v2f a02 = m00*m02 + m10*m12 + m20*m22;
    v2f a12 = m01*m02 + m11*m12 + m21*m22;

    v2f v00 = (v2f)1.0f, v01 = (v2f)0.0f, v02 = (v2f)0.0f;
    v2f v10 = (v2f)0.0f, v11 = (v2f)1.0f, v12 = (v2f)0.0f;
    v2f v20 = (v2f)0.0f, v21 = (v2f)0.0f, v22 = (v2f)1.0f;

    #pragma unroll
    for (int sw = 0; sw < 4; ++sw) {
        jrot2(a00, a11, a01, a02, a12, v00, v10, v20, v01, v11, v21); // (0,1) r=2
        jrot2(a00, a22, a02, a01, a12, v00, v10, v20, v02, v12, v22); // (0,2) r=1
        jrot2(a11, a22, a12, a01, a02, v01, v11, v21, v02, v12, v22); // (1,2) r=0
    }

    // Sort eigenvalues descending; column swap + negate keeps det(V)=+1
    v2f t;
    {
        v2i c01 = a00 < a11;
        t = a00; a00 = sel2(c01, a11, a00); a11 = sel2(c01, t, a11);
        t = v00; v00 = sel2(c01, v01, v00); v01 = sel2(c01, -t, v01);
        t = v10; v10 = sel2(c01, v11, v10); v11 = sel2(c01, -t, v11);
        t = v20; v20 = sel2(c01, v21, v20); v21 = sel2(c01, -t, v21);
    }
    {
        v2i c02 = a00 < a22;
        t = a00; a00 = sel2(c02, a22, a00); a22 = sel2(c02, t, a22);
        t = v00; v00 = sel2(c02, v02, v00); v02 = sel2(c02, -t, v02);
        t = v10; v10 = sel2(c02, v12, v10); v12 = sel2(c02, -t, v12);
        t = v20; v20 = sel2(c02, v22, v20); v22 = sel2(c02, -t, v22);
    }
    {
        v2i c12 = a11 < a22;
        t = a11; a11 = sel2(c12, a22, a11); a22 = sel2(c12, t, a22);
        t = v01; v01 = sel2(c12, v02, v01); v02 = sel2(c12, -t, v02);
        t = v11; v11 = sel2(c12, v12, v11); v12 = sel2(c12, -t, v12);
        t = v21; v21 = sel2(c12, v22, v21); v22 = sel2(c12, -t, v22);
    }

    // B = M * V
    v2f b00 = m00*v00 + m01*v10 + m02*v20;
    v2f b01 = m00*v01 + m01*v11 + m02*v21;
    v2f b02 = m00*v02 + m01*v12 + m02*v22;
    v2f b10 = m10*v00 + m11*v10 + m12*v20;
    v2f b11 = m10*v01 + m11*v11 + m12*v21;
    v2f b12 = m10*v02 + m11*v12 + m12*v22;
    v2f b20 = m20*v00 + m21*v10 + m22*v20;
    v2f b21 = m20*v01 + m21*v11 + m22*v21;
    v2f b22 = m20*v02 + m21*v12 + m22*v22;

    v2f u00 = (v2f)1.0f, u01 = (v2f)0.0f, u02 = (v2f)0.0f;
    v2f u10 = (v2f)0.0f, u11 = (v2f)1.0f, u12 = (v2f)0.0f;
    v2f u20 = (v2f)0.0f, u21 = (v2f)0.0f, u22 = (v2f)1.0f;

    // Givens QR of B: zero (1,0), (2,0), (2,1)
    givens2(b00, b10, b00, b01, b02, b10, b11, b12,
            u00, u10, u20, u01, u11, u21);
    givens2(b00, b20, b00, b01, b02, b20, b21, b22,
            u00, u10, u20, u02, u12, u22);
    givens2(b11, b21, b10, b11, b12, b20, b21, b22,
            u01, u11, u21, u02, u12, u22);

    // R = U * V^T
    r00 = u00*v00 + u01*v01 + u02*v02;
    r01 = u00*v10 + u01*v11 + u02*v12;
    r02 = u00*v20 + u01*v21 + u02*v22;
    r10 = u10*v00 + u11*v01 + u12*v02;
    r11 = u10*v10 + u11*v11 + u12*v12;
    r12 = u10*v20 + u11*v21 + u12*v22;
    r20 = u20*v00 + u21*v01 + u22*v02;
    r21 = u20*v10 + u21*v11 + u22*v12;
    r22 = u20*v20 + u21*v21 + u22*v22;
}

__global__ __launch_bounds__(TPB) void svdo_kernel(const float* __restrict__ x,
                                                   float* __restrict__ out,
                                                   int nmat)
{
    const int g  = blockIdx.x * TPB + threadIdx.x;
    const int m4 = g * 4;
    if (m4 >= nmat) return;
    const size_t base = (size_t)m4 * 9;
    const bool full = (m4 + 4 <= nmat);

    // 36 input floats, named (no runtime-indexed arrays -> no scratch)
    float x0,x1,x2,x3,x4,x5,x6,x7,x8,x9,x10,x11,x12,x13,x14,x15,x16,x17,
          x18,x19,x20,x21,x22,x23,x24,x25,x26,x27,x28,x29,x30,x31,x32,x33,x34,x35;

    if (full) {
        // 144 B/thread = nine 16B-aligned float4 loads (144 = 9*16)
        const float4* p = (const float4*)(x + base);
        float4 q0=p[0], q1=p[1], q2=p[2], q3=p[3], q4=p[4], q5=p[5], q6=p[6], q7=p[7], q8=p[8];
        x0 =q0.x; x1 =q0.y; x2 =q0.z; x3 =q0.w;
        x4 =q1.x; x5 =q1.y; x6 =q1.z; x7 =q1.w;
        x8 =q2.x; x9 =q2.y; x10=q2.z; x11=q2.w;
        x12=q3.x; x13=q3.y; x14=q3.z; x15=q3.w;
        x16=q4.x; x17=q4.y; x18=q4.z; x19=q4.w;
        x20=q5.x; x21=q5.y; x22=q5.z; x23=q5.w;
        x24=q6.x; x25=q6.y; x26=q6.z; x27=q6.w;
        x28=q7.x; x29=q7.y; x30=q7.z; x31=q7.w;
        x32=q8.x; x33=q8.y; x34=q8.z; x35=q8.w;
    } else {
        const int nf = (nmat - m4) * 9;
        x0 =(0 <nf)?x[base+0 ]:0.f; x1 =(1 <nf)?x[base+1 ]:0.f; x2 =(2 <nf)?x[base+2 ]:0.f;
        x3 =(3 <nf)?x[base+3 ]:0.f; x4 =(4 <nf)?x[base+4 ]:0.f; x5 =(5 <nf)?x[base+5 ]:0.f;
        x6 =(6 <nf)?x[base+6 ]:0.f; x7 =(7 <nf)?x[base+7 ]:0.f; x8 =(8 <nf)?x[base+8 ]:0.f;
        x9 =(9 <nf)?x[base+9 ]:0.f; x10=(10<nf)?x[base+10]:0.f; x11=(11<nf)?x[base+11]:0.f;
        x12=(12<nf)?x[base+12]:0.f; x13=(13<nf)?x[base+13]:0.f; x14=(14<nf)?x[base+14]:0.f;
        x15=(15<nf)?x[base+15]:0.f; x16=(16<nf)?x[base+16]:0.f; x17=(17<nf)?x[base+17]:0.f;
        x18=(18<nf)?x[base+18]:0.f; x19=(19<nf)?x[base+19]:0.f; x20=(20<nf)?x[base+20]:0.f;
        x21=(21<nf)?x[base+21]:0.f; x22=(22<nf)?x[base+22]:0.f; x23=(23<nf)?x[base+23]:0.f;
        x24=(24<nf)?x[base+24]:0.f; x25=(25<nf)?x[base+25]:0.f; x26=(26<nf)?x[base+26]:0.f;
        x27=(27<nf)?x[base+27]:0.f; x28=(28<nf)?x[base+28]:0.f; x29=(29<nf)?x[base+29]:0.f;
        x30=(30<nf)?x[base+30]:0.f; x31=(31<nf)?x[base+31]:0.f; x32=(32<nf)?x[base+32]:0.f;
        x33=(33<nf)?x[base+33]:0.f; x34=(34<nf)?x[base+34]:0.f; x35=(35<nf)?x[base+35]:0.f;
    }

    // Stream A = matrices {0,1}; Stream B = matrices {2,3}. Two independent
    // dependency chains per thread -> 2x latency hiding.
    v2f ra00, ra01, ra02, ra10, ra11, ra12, ra20, ra21, ra22;
    v2f rb00, rb01, rb02, rb10, rb11, rb12, rb20, rb21, rb22;

    solve2((v2f){x0 ,x9 }, (v2f){x1 ,x10}, (v2f){x2 ,x11},
           (v2f){x3 ,x12}, (v2f){x4 ,x13}, (v2f){x5 ,x14},
           (v2f){x6 ,x15}, (v2f){x7 ,x16}, (v2f){x8 ,x17},
           ra00, ra01, ra02, ra10, ra11, ra12, ra20, ra21, ra22);

    solve2((v2f){x18,x27}, (v2f){x19,x28}, (v2f){x20,x29},
           (v2f){x21,x30}, (v2f){x22,x31}, (v2f){x23,x32},
           (v2f){x24,x33}, (v2f){x25,x34}, (v2f){x26,x35},
           rb00, rb01, rb02, rb10, rb11, rb12, rb20, rb21, rb22);

    // Output floats y0..y35
    float y0 =ra00.x, y1 =ra01.x, y2 =ra02.x, y3 =ra10.x, y4 =ra11.x, y5 =ra12.x,
          y6 =ra20.x, y7 =ra21.x, y8 =ra22.x,
          y9 =ra00.y, y10=ra01.y, y11=ra02.y, y12=ra10.y, y13=ra11.y, y14=ra12.y,
          y15=ra20.y, y16=ra21.y, y17=ra22.y,
          y18=rb00.x, y19=rb01.x, y20=rb02.x, y21=rb10.x, y22=rb11.x, y23=rb12.x,
          y24=rb20.x, y25=rb21.x, y26=rb22.x,
          y27=rb00.y, y28=rb01.y, y29=rb02.y, y30=rb10.y, y31=rb11.y, y32=rb12.y,
          y33=rb20.y, y34=rb21.y, y35=rb22.y;

    if (full) {
        float4* o = (float4*)(out + base);
        o[0] = make_float4(y0 ,y1 ,y2 ,y3 );
        o[1] = make_float4(y4 ,y5 ,y6 ,y7 );
        o[2] = make_float4(y8 ,y9 ,y10,y11);
        o[3] = make_float4(y12,y13,y14,y15);
        o[4] = make_float4(y16,y17,y18,y19);
        o[5] = make_float4(y20,y21,y22,y23);
        o[6] = make_float4(y24,y25,y26,y27);
        o[7] = make_float4(y28,y29,y30,y31);
        o[8] = make_float4(y32,y33,y34,y35);
    } else {
        const int nf = (nmat - m4) * 9;
        if (0 <nf) out[base+0 ]=y0 ; if (1 <nf) out[base+1 ]=y1 ; if (2 <nf) out[base+2 ]=y2 ;
        if (3 <nf) out[base+3 ]=y3 ; if (4 <nf) out[base+4 ]=y4 ; if (5 <nf) out[base+5 ]=y5 ;
        if (6 <nf) out[base+6 ]=y6 ; if (7 <nf) out[base+7 ]=y7 ; if (8 <nf) out[base+8 ]=y8 ;
        if (9 <nf) out[base+9 ]=y9 ; if (10<nf) out[base+10]=y10; if (11<nf) out[base+11]=y11;
        if (12<nf) out[base+12]=y12; if (13<nf) out[base+13]=y13; if (14<nf) out[base+14]=y14;
        if (15<nf) out[base+15]=y15; if (16<nf) out[base+16]=y16; if (17<nf) out[base+17]=y17;
        if (18<nf) out[base+18]=y18; if (19<nf) out[base+19]=y19; if (20<nf) out[base+20]=y20;
        if (21<nf) out[base+21]=y21; if (22<nf) out[base+22]=y22; if (23<nf) out[base+23]=y23;
        if (24<nf) out[base+24]=y24; if (25<nf) out[base+25]=y25; if (26<nf) out[base+26]=y26;
        if (27<nf) out[base+27]=y27; if (28<nf) out[base+28]=y28; if (29<nf) out[base+29]=y29;
        if (30<nf) out[base+30]=y30; if (31<nf) out[base+31]=y31; if (32<nf) out[base+32]=y32;
        if (33<nf) out[base+33]=y33; if (34<nf) out[base+34]=y34; if (35<nf) out[base+35]=y35;
    }
}

extern "C" void kernel_launch(void* const* d_in, const int* in_sizes, int n_in,
                              void* d_out, int out_size, void* d_ws, size_t ws_size,
                              hipStream_t stream)
{
    (void)n_in; (void)d_ws; (void)ws_size; (void)out_size;
    const float* x = (const float*)d_in[0];
    float* out = (float*)d_out;
    const int nmat = in_sizes[0] / 9;
    const int mats_per_block = TPB * 4;
    const int grid = (nmat + mats_per_block - 1) / mats_per_block;
    svdo_kernel<<<grid, TPB, 0, stream>>>(x, out, nmat);
}

// Round 4
// 39.058 us; speedup vs baseline: 1.1198x; 1.1198x over previous
//
#include <hip/hip_runtime.h>

#define TPB 256
#define MPB 512                       // matrices per tile
#define TILE_FLOATS (MPB * 9)         // 4608 floats = 18432 B
#define TILE_F4 (TILE_FLOATS / 4)     // 1152 float4 per tile

typedef float v2f __attribute__((ext_vector_type(2)));
typedef int   v2i __attribute__((ext_vector_type(2)));

static __device__ __forceinline__ v2f sqrt2(v2f a){
    v2f r; r.x = __builtin_amdgcn_sqrtf(a.x); r.y = __builtin_amdgcn_sqrtf(a.y); return r;
}
static __device__ __forceinline__ v2f rsq2(v2f a){
    v2f r; r.x = __builtin_amdgcn_rsqf(a.x); r.y = __builtin_amdgcn_rsqf(a.y); return r;
}
static __device__ __forceinline__ v2f csign2(v2f x, v2f y){
    v2f r; r.x = copysignf(x.x, y.x); r.y = copysignf(x.y, y.y); return r;
}
static __device__ __forceinline__ v2f fabs2(v2f x){
    v2f r; r.x = fabsf(x.x); r.y = fabsf(x.y); return r;
}
static __device__ __forceinline__ v2f sel2(v2i m, v2f a, v2f b){
    v2f r; r.x = m.x ? a.x : b.x; r.y = m.y ? a.y : b.y; return r;
}
static __device__ __forceinline__ void rot2(v2f &p, v2f &q, v2f c, v2f s){
    v2f x = p, y = q; p = c*x - s*y; q = s*x + c*y;
}
static __device__ __forceinline__ void rotg2(v2f &p, v2f &q, v2f c, v2f s){
    v2f x = p, y = q; p = c*x + s*y; q = c*y - s*x;
}

static __device__ __forceinline__ void jrot2(v2f &app, v2f &aqq, v2f &apq,
                                             v2f &arp, v2f &arq,
                                             v2f &v0p, v2f &v1p, v2f &v2p,
                                             v2f &v0q, v2f &v1q, v2f &v2q)
{
    v2f d   = aqq - app;
    v2f w   = apq + apq;
    v2f nrm = d*d + w*w;
    v2f rr  = sqrt2(nrm);
    v2f sr  = csign2(rr, d);
    v2f den = d + sr;
    v2f inv = rsq2(den*den + w*w);
    v2f c   = fabs2(den) * inv;
    v2f s   = w * csign2(inv, den);
    v2i tiny = nrm < (v2f)1e-30f;
    c = sel2(tiny, (v2f)1.0f, c);
    s = sel2(tiny, (v2f)0.0f, s);
    v2f sum = app + aqq;
    v2f lo  = 0.5f*(sum - sr);
    app = lo; aqq = sum - lo; apq = (v2f)0.0f;
    rot2(arp, arq, c, s);
    rot2(v0p, v0q, c, s);
    rot2(v1p, v1q, c, s);
    rot2(v2p, v2q, c, s);
}

static __device__ __forceinline__ void givens2(v2f a1, v2f a2,
    v2f &bi0, v2f &bi1, v2f &bi2, v2f &bj0, v2f &bj1, v2f &bj2,
    v2f &ui0, v2f &ui1, v2f &ui2, v2f &uj0, v2f &uj1, v2f &uj2)
{
    v2f d  = a1*a1 + a2*a2;
    v2f rr = rsq2(d);
    v2i ok = d > (v2f)1e-30f;
    v2f c  = sel2(ok, a1*rr, (v2f)1.0f);
    v2f s  = sel2(ok, a2*rr, (v2f)0.0f);
    rotg2(bi0, bj0, c, s);
    rotg2(bi1, bj1, c, s);
    rotg2(bi2, bj2, c, s);
    rotg2(ui0, uj0, c, s);
    rotg2(ui1, uj1, c, s);
    rotg2(ui2, uj2, c, s);
}

static __device__ __forceinline__ void solve2(
    v2f m00, v2f m01, v2f m02,
    v2f m10, v2f m11, v2f m12,
    v2f m20, v2f m21, v2f m22,
    v2f &r00, v2f &r01, v2f &r02,
    v2f &r10, v2f &r11, v2f &r12,
    v2f &r20, v2f &r21, v2f &r22)
{
    v2f a00 = m00*m00 + m10*m10 + m20*m20;
    v2f a11 = m01*m01 + m11*m11 + m21*m21;
    v2f a22 = m02*m02 + m12*m12 + m22*m22;
    v2f a01 = m00*m01 + m10*m11 + m20*m21;
    v2f a02 = m00*m02 + m10*m12 + m20*m22;
    v2f a12 = m01*m02 + m11*m12 + m21*m22;

    v2f v00 = (v2f)1.0f, v01 = (v2f)0.0f, v02 = (v2f)0.0f;
    v2f v10 = (v2f)0.0f, v11 = (v2f)1.0f, v12 = (v2f)0.0f;
    v2f v20 = (v2f)0.0f, v21 = (v2f)0.0f, v22 = (v2f)1.0f;

    #pragma unroll
    for (int sw = 0; sw < 4; ++sw) {
        jrot2(a00, a11, a01, a02, a12, v00, v10, v20, v01, v11, v21);
        jrot2(a00, a22, a02, a01, a12, v00, v10, v20, v02, v12, v22);
        jrot2(a11, a22, a12, a01, a02, v01, v11, v21, v02, v12, v22);
    }

    v2f t;
    {
        v2i c01 = a00 < a11;
        t = a00; a00 = sel2(c01, a11, a00); a11 = sel2(c01, t, a11);
        t = v00; v00 = sel2(c01, v01, v00); v01 = sel2(c01, -t, v01);
        t = v10; v10 = sel2(c01, v11, v10); v11 = sel2(c01, -t, v11);
        t = v20; v20 = sel2(c01, v21, v20); v21 = sel2(c01, -t, v21);
    }
    {
        v2i c02 = a00 < a22;
        t = a00; a00 = sel2(c02, a22, a00); a22 = sel2(c02, t, a22);
        t = v00; v00 = sel2(c02, v02, v00); v02 = sel2(c02, -t, v02);
        t = v10; v10 = sel2(c02, v12, v10); v12 = sel2(c02, -t, v12);
        t = v20; v20 = sel2(c02, v22, v20); v22 = sel2(c02, -t, v22);
    }
    {
        v2i c12 = a11 < a22;
        t = a11; a11 = sel2(c12, a22, a11); a22 = sel2(c12, t, a22);
        t = v01; v01 = sel2(c12, v02, v01); v02 = sel2(c12, -t, v02);
        t = v11; v11 = sel2(c12, v12, v11); v12 = sel2(c12, -t, v12);
        t = v21; v21 = sel2(c12, v22, v21); v22 = sel2(c12, -t, v22);
    }

    v2f b00 = m00*v00 + m01*v10 + m02*v20;
    v2f b01 = m00*v01 + m01*v11 + m02*v21;
    v2f b02 = m00*v02 + m01*v12 + m02*v22;
    v2f b10 = m10*v00 + m11*v10 + m12*v20;
    v2f b11 = m10*v01 + m11*v11 + m12*v21;
    v2f b12 = m10*v02 + m11*v12 + m12*v22;
    v2f b20 = m20*v00 + m21*v10 + m22*v20;
    v2f b21 = m20*v01 + m21*v11 + m22*v21;
    v2f b22 = m20*v02 + m21*v12 + m22*v22;

    v2f u00 = (v2f)1.0f, u01 = (v2f)0.0f, u02 = (v2f)0.0f;
    v2f u10 = (v2f)0.0f, u11 = (v2f)1.0f, u12 = (v2f)0.0f;
    v2f u20 = (v2f)0.0f, u21 = (v2f)0.0f, u22 = (v2f)1.0f;

    givens2(b00, b10, b00, b01, b02, b10, b11, b12,
            u00, u10, u20, u01, u11, u21);
    givens2(b00, b20, b00, b01, b02, b20, b21, b22,
            u00, u10, u20, u02, u12, u22);
    givens2(b11, b21, b10, b11, b12, b20, b21, b22,
            u01, u11, u21, u02, u12, u22);

    r00 = u00*v00 + u01*v01 + u02*v02;
    r01 = u00*v10 + u01*v11 + u02*v12;
    r02 = u00*v20 + u01*v21 + u02*v22;
    r10 = u10*v00 + u11*v01 + u12*v02;
    r11 = u10*v10 + u11*v11 + u12*v12;
    r12 = u10*v20 + u11*v21 + u12*v22;
    r20 = u20*v00 + u21*v01 + u22*v02;
    r21 = u20*v10 + u21*v11 + u22*v12;
    r22 = u20*v20 + u21*v21 + u22*v22;
}

static __device__ __forceinline__ float4 ld_f4(const float* __restrict__ x, long f, long ntotf){
    if (f + 4 <= ntotf) return *(const float4*)(x + f);
    float4 r = make_float4(0.f, 0.f, 0.f, 0.f);
    if (f     < ntotf) r.x = x[f];
    if (f + 1 < ntotf) r.y = x[f + 1];
    if (f + 2 < ntotf) r.z = x[f + 2];
    if (f + 3 < ntotf) r.w = x[f + 3];
    return r;
}
static __device__ __forceinline__ void st_f4(float* __restrict__ o, long f, float4 v, long ntotf){
    if (f + 4 <= ntotf) { *(float4*)(o + f) = v; return; }
    if (f     < ntotf) o[f]     = v.x;
    if (f + 1 < ntotf) o[f + 1] = v.y;
    if (f + 2 < ntotf) o[f + 2] = v.z;
    if (f + 3 < ntotf) o[f + 3] = v.w;
}

// Pipelined persistent-tile kernel: each block grid-strides over tiles of 512
// matrices. Next tile's global loads are ISSUED before computing the current
// tile, so HBM requests stay outstanding through the ~1400-cycle compute
// phase (Little's law: ~18 KB in flight per block -> BW-saturating).
__global__ __launch_bounds__(TPB) void svdo_kernel(const float* __restrict__ x,
                                                   float* __restrict__ out,
                                                   int nmat, int ntiles, int G)
{
    __shared__ float lds[2 * TILE_FLOATS];
    const int tid = threadIdx.x;
    const long ntotf = (long)nmat * 9;

    int tile = blockIdx.x;
    float4 q0, q1, q2, q3;
    float4 q4 = make_float4(0.f, 0.f, 0.f, 0.f);

    // Prologue: stage tile -> buf0
    {
        const long fb = (long)tile * TILE_FLOATS;
        q0 = ld_f4(x, fb + (long)(tid       ) * 4, ntotf);
        q1 = ld_f4(x, fb + (long)(tid +  256) * 4, ntotf);
        q2 = ld_f4(x, fb + (long)(tid +  512) * 4, ntotf);
        q3 = ld_f4(x, fb + (long)(tid +  768) * 4, ntotf);
        if (tid < TILE_F4 - 1024) q4 = ld_f4(x, fb + (long)(tid + 1024) * 4, ntotf);
        float4* p = (float4*)&lds[0];
        p[tid] = q0; p[tid + 256] = q1; p[tid + 512] = q2; p[tid + 768] = q3;
        if (tid < TILE_F4 - 1024) p[tid + 1024] = q4;
    }

    int cur = 0;
    while (true) {
        const int  next      = tile + G;
        const bool have_next = next < ntiles;

        __syncthreads();   // buf[cur] fully staged; all store-reads of buf[cur^1] done

        // Issue next tile's loads NOW — outstanding through the compute phase.
        if (have_next) {
            const long fb = (long)next * TILE_FLOATS;
            q0 = ld_f4(x, fb + (long)(tid       ) * 4, ntotf);
            q1 = ld_f4(x, fb + (long)(tid +  256) * 4, ntotf);
            q2 = ld_f4(x, fb + (long)(tid +  512) * 4, ntotf);
            q3 = ld_f4(x, fb + (long)(tid +  768) * 4, ntotf);
            if (tid < TILE_F4 - 1024) q4 = ld_f4(x, fb + (long)(tid + 1024) * 4, ntotf);
        }

        // Compute 2 matrices from buf[cur] (own region only — no cross-thread)
        float* B = &lds[cur * TILE_FLOATS];
        {
            const float* p0 = &B[tid * 9];
            const float* p1 = &B[(tid + 256) * 9];
            v2f m00 = {p0[0], p1[0]}, m01 = {p0[1], p1[1]}, m02 = {p0[2], p1[2]};
            v2f m10 = {p0[3], p1[3]}, m11 = {p0[4], p1[4]}, m12 = {p0[5], p1[5]};
            v2f m20 = {p0[6], p1[6]}, m21 = {p0[7], p1[7]}, m22 = {p0[8], p1[8]};

            v2f r00, r01, r02, r10, r11, r12, r20, r21, r22;
            solve2(m00, m01, m02, m10, m11, m12, m20, m21, m22,
                   r00, r01, r02, r10, r11, r12, r20, r21, r22);

            float* o0 = &B[tid * 9];
            o0[0]=r00.x; o0[1]=r01.x; o0[2]=r02.x;
            o0[3]=r10.x; o0[4]=r11.x; o0[5]=r12.x;
            o0[6]=r20.x; o0[7]=r21.x; o0[8]=r22.x;
            float* o1 = &B[(tid + 256) * 9];
            o1[0]=r00.y; o1[1]=r01.y; o1[2]=r02.y;
            o1[3]=r10.y; o1[4]=r11.y; o1[5]=r12.y;
            o1[6]=r20.y; o1[7]=r21.y; o1[8]=r22.y;
        }

        // Land prefetched tile into the other buffer (vmcnt wait lands HERE,
        // after compute — not before it).
        if (have_next) {
            float4* p = (float4*)&lds[(cur ^ 1) * TILE_FLOATS];
            p[tid] = q0; p[tid + 256] = q1; p[tid + 512] = q2; p[tid + 768] = q3;
            if (tid < TILE_F4 - 1024) p[tid + 1024] = q4;
        }

        __syncthreads();   // results visible; next buffer staged

        // Coalesced store of results from buf[cur]
        {
            const float4* p = (const float4*)B;
            const long fb = (long)tile * TILE_FLOATS;
            st_f4(out, fb + (long)(tid       ) * 4, p[tid      ], ntotf);
            st_f4(out, fb + (long)(tid +  256) * 4, p[tid +  256], ntotf);
            st_f4(out, fb + (long)(tid +  512) * 4, p[tid +  512], ntotf);
            st_f4(out, fb + (long)(tid +  768) * 4, p[tid +  768], ntotf);
            if (tid < TILE_F4 - 1024)
                st_f4(out, fb + (long)(tid + 1024) * 4, p[tid + 1024], ntotf);
        }

        if (!have_next) break;
        tile = next;
        cur ^= 1;
    }
}

extern "C" void kernel_launch(void* const* d_in, const int* in_sizes, int n_in,
                              void* d_out, int out_size, void* d_ws, size_t ws_size,
                              hipStream_t stream)
{
    (void)n_in; (void)d_ws; (void)ws_size; (void)out_size;
    const float* x = (const float*)d_in[0];
    float* out = (float*)d_out;
    const int nmat = in_sizes[0] / 9;
    const int ntiles = (nmat + MPB - 1) / MPB;
    const int G = ntiles < 1024 ? ntiles : 1024;
    svdo_kernel<<<G, TPB, 0, stream>>>(x, out, nmat, ntiles, G);
}